// Round 5
// baseline (493.843 us; speedup 1.0000x reference)
//
#include <hip/hip_runtime.h>
#include <hip/hip_cooperative_groups.h>

namespace cg = cooperative_groups;

// Problem constants (match reference setup_inputs()).
#define Nn 50000
#define Rr 4
#define Dd 5
#define Ee 5000000
#define Bb 4
#define NRr (Nn * Rr)   // 200000
#define NDd (Nn * Dd)   // 250000

typedef int   v4i __attribute__((ext_vector_type(4)));
typedef float v4f __attribute__((ext_vector_type(4)));

struct P {
    const float* inputs; const float* z_buf; const float* v; const float* r;
    const float* asc1; const float* asc2; const float* psc_rise; const float* psc;
    const float* rec_w; const int* rec_rows; const int* rec_cols;
    const float* syn_decay; const float* psc_initial; const float* t_ref;
    const float* asc_amps; const float* k; const float* v_th; const float* e_l;
    const float* v_reset; const float* g; const float* decay;
    const float* current_factor; const float* vscale; const float* voffset;
    float* out; float* i_rec; unsigned char* z_pack;
};

// ---------------------------------------------------------------------------
// Phase 1: zero i_rec + pack z_buf into per-column 4-bit batch masks.
// ---------------------------------------------------------------------------
__device__ __forceinline__ void phase1_body(const P& p, int tid, int nthreads) {
    for (int i = tid; i < Bb * NRr / 4; i += nthreads)
        ((float4*)p.i_rec)[i] = make_float4(0.f, 0.f, 0.f, 0.f);
    for (int i = tid; i < NDd; i += nthreads) {
        unsigned m = 0;
#pragma unroll
        for (int b = 0; b < Bb; ++b)
            if (p.z_buf[(size_t)b * NDd + i] != 0.0f) m |= (1u << b);
        p.z_pack[i] = (unsigned char)m;
    }
}

// ---------------------------------------------------------------------------
// Phase 2: sparse recurrent scatter. z_pack gate (~95% of columns dead) then
// up to 4 fire-and-forget atomics per hit. Edge streams (60 MB, read once)
// use nontemporal loads so they don't evict z_pack/i_rec from L2.
// ---------------------------------------------------------------------------
__device__ __forceinline__ void phase2_body(const P& p, int tid, int nthreads) {
    const v4i* cols4 = (const v4i*)p.rec_cols;
    const v4i* rows4 = (const v4i*)p.rec_rows;
    const v4f* w4    = (const v4f*)p.rec_w;
    const unsigned char* zp = p.z_pack;
    float* i_rec = p.i_rec;
    for (int i = tid; i < Ee / 4; i += nthreads) {
        v4i c = __builtin_nontemporal_load(&cols4[i]);
        unsigned m0 = zp[c.x], m1 = zp[c.y], m2 = zp[c.z], m3 = zp[c.w];
        if (!(m0 | m1 | m2 | m3)) continue;
        v4i rw = __builtin_nontemporal_load(&rows4[i]);
        v4f w  = __builtin_nontemporal_load(&w4[i]);
        auto do_edge = [&](unsigned mm, int row, float wv) {
            if (mm & 1u) atomicAdd(&i_rec[0 * NRr + row], wv);
            if (mm & 2u) atomicAdd(&i_rec[1 * NRr + row], wv);
            if (mm & 4u) atomicAdd(&i_rec[2 * NRr + row], wv);
            if (mm & 8u) atomicAdd(&i_rec[3 * NRr + row], wv);
        };
        do_edge(m0, rw.x, w.x);
        do_edge(m1, rw.y, w.y);
        do_edge(m2, rw.z, w.z);
        do_edge(m3, rw.w, w.w);
    }
}

// ---------------------------------------------------------------------------
// Phase 3: elementwise neuron update + output assembly (verified math).
// Output layout per batch (18*N floats):
//   [0,N)=new_z [N,2N)=out_v [2N,3N)=new_r [3N,4N)=asc1 [4N,5N)=asc2
//   [5N,9N)=psc_rise [9N,13N)=psc [13N,18N)=shifted z_buf
// ---------------------------------------------------------------------------
__device__ __forceinline__ void phase3_body(const P& p, int tid, int nthreads) {
    for (int idx = tid; idx < Bb * Nn; idx += nthreads) {
        int b = idx / Nn;
        int n = idx - b * Nn;
        const size_t bn  = (size_t)b * Nn + n;
        const size_t bnr = (size_t)b * NRr + (size_t)n * 4;

        float prev_z = p.z_buf[(size_t)b * NDd + n];

        float4 ir  = *(const float4*)(p.i_rec + bnr);
        float4 in4 = *(const float4*)(p.inputs + bnr);
        float4 pr  = *(const float4*)(p.psc_rise + bnr);
        float4 pc  = *(const float4*)(p.psc + bnr);
        float4 sd  = *(const float4*)(p.syn_decay + (size_t)n * 4);
        float4 pi  = *(const float4*)(p.psc_initial + (size_t)n * 4);

        float4 npr, npc;
        npr.x = sd.x * pr.x + (ir.x + in4.x) * pi.x;
        npr.y = sd.y * pr.y + (ir.y + in4.y) * pi.y;
        npr.z = sd.z * pr.z + (ir.z + in4.z) * pi.z;
        npr.w = sd.w * pr.w + (ir.w + in4.w) * pi.w;
        npc.x = pc.x * sd.x + sd.x * pr.x;
        npc.y = pc.y * sd.y + sd.y * pr.y;
        npc.z = pc.z * sd.z + sd.z * pr.z;
        npc.w = pc.w * sd.w + sd.w * pr.w;

        float input_current = pc.x + pc.y + pc.z + pc.w;   // OLD psc

        float tr    = p.t_ref[n];
        float new_r = fmaxf(p.r[bn] + prev_z * tr - 1.0f, 0.0f);

        float2 kv = *(const float2*)(p.k + (size_t)n * 2);
        float2 aa = *(const float2*)(p.asc_amps + (size_t)n * 2);
        float kk0 = 1.0f / (1.0f + expf(-kv.x));
        float kk1 = 1.0f / (1.0f + expf(-kv.y));
        float a1 = p.asc1[bn];
        float a2 = p.asc2[bn];
        float na1 = expf(-kk0) * a1 + prev_z * aa.x;
        float na2 = expf(-kk1) * a2 + prev_z * aa.y;

        float vth = p.v_th[n];
        float el  = p.e_l[n];
        float reset_current = prev_z * (p.v_reset[n] - vth);
        float c1 = input_current + a1 + a2 + p.g[n] * el;  // OLD asc values
        float new_v = p.decay[n] * p.v[bn] + p.current_factor[n] * c1 + reset_current;

        float v_sc = (new_v - vth) / (vth - el);
        float new_z = (v_sc > 0.0f) ? 1.0f : 0.0f;
        if (new_r > 0.0f) new_z = 0.0f;

        float out_v = new_v * p.vscale[n] + p.voffset[n];

        float* ob = p.out + (size_t)b * 18 * Nn;
        ob[n]            = new_z;
        ob[Nn + n]       = out_v;
        ob[2 * Nn + n]   = new_r;
        ob[3 * Nn + n]   = na1;
        ob[4 * Nn + n]   = na2;
        *(float4*)(ob + 5 * Nn + (size_t)n * 4) = npr;
        *(float4*)(ob + 9 * Nn + (size_t)n * 4) = npc;
        ob[13 * Nn + n] = new_z;
#pragma unroll
        for (int d = 0; d < Dd - 1; ++d)
            ob[14 * Nn + (size_t)d * Nn + n] =
                p.z_buf[(size_t)b * NDd + (size_t)d * Nn + n];
    }
}

// ---------------------------------------------------------------------------
// Fused cooperative kernel: one dispatch, grid.sync() between phases
// (device-scope acq/rel fences handle cross-XCD L2 visibility).
// ---------------------------------------------------------------------------
__global__ __launch_bounds__(256, 4) void fused_kernel(P p) {
    cg::grid_group grid = cg::this_grid();
    const int tid = blockIdx.x * 256 + threadIdx.x;
    const int nthreads = gridDim.x * 256;
    phase1_body(p, tid, nthreads);
    grid.sync();
    phase2_body(p, tid, nthreads);
    grid.sync();
    phase3_body(p, tid, nthreads);
}

// Fallback wrappers (used only if cooperative launch is rejected).
__global__ __launch_bounds__(256) void phase1_kernel(P p) {
    phase1_body(p, blockIdx.x * 256 + threadIdx.x, gridDim.x * 256);
}
__global__ __launch_bounds__(256) void phase2_kernel(P p) {
    phase2_body(p, blockIdx.x * 256 + threadIdx.x, gridDim.x * 256);
}
__global__ __launch_bounds__(256) void phase3_kernel(P p) {
    phase3_body(p, blockIdx.x * 256 + threadIdx.x, gridDim.x * 256);
}

extern "C" void kernel_launch(void* const* d_in, const int* in_sizes, int n_in,
                              void* d_out, int out_size, void* d_ws, size_t ws_size,
                              hipStream_t stream) {
    P p;
    p.inputs        = (const float*)d_in[0];
    p.z_buf         = (const float*)d_in[1];
    p.v             = (const float*)d_in[2];
    p.r             = (const float*)d_in[3];
    p.asc1          = (const float*)d_in[4];
    p.asc2          = (const float*)d_in[5];
    p.psc_rise      = (const float*)d_in[6];
    p.psc           = (const float*)d_in[7];
    p.rec_w         = (const float*)d_in[8];
    p.rec_rows      = (const int*)d_in[9];
    p.rec_cols      = (const int*)d_in[10];
    p.syn_decay     = (const float*)d_in[11];
    p.psc_initial   = (const float*)d_in[12];
    p.t_ref         = (const float*)d_in[13];
    p.asc_amps      = (const float*)d_in[14];
    p.k             = (const float*)d_in[15];
    p.v_th          = (const float*)d_in[16];
    p.e_l           = (const float*)d_in[17];
    p.v_reset       = (const float*)d_in[18];
    p.g             = (const float*)d_in[19];
    p.decay         = (const float*)d_in[20];
    p.current_factor= (const float*)d_in[21];
    p.vscale        = (const float*)d_in[22];
    p.voffset       = (const float*)d_in[23];
    p.out           = (float*)d_out;
    // Workspace: i_rec f32[B*N*R] @0 (3.2 MB) | z_pack u8[N*D] @3,200,000
    p.i_rec  = (float*)d_ws;
    p.z_pack = (unsigned char*)d_ws + 3200000;

    // 1024 blocks x 256 thr = 4 blocks/CU (launch_bounds(256,4) caps VGPR at
    // 128 so co-residency holds); grid-stride bodies are size-agnostic.
    void* args[] = {(void*)&p};
    hipError_t err = hipLaunchCooperativeKernel(
        reinterpret_cast<void*>(fused_kernel), dim3(1024), dim3(256),
        args, 0, stream);
    if (err != hipSuccess) {
        // Fallback: proven 3-dispatch path.
        phase1_kernel<<<(NDd + 255) / 256, 256, 0, stream>>>(p);
        phase2_kernel<<<(Ee / 4 + 255) / 256, 256, 0, stream>>>(p);
        phase3_kernel<<<(Bb * Nn + 255) / 256, 256, 0, stream>>>(p);
    }
}

// Round 6
// 203.157 us; speedup vs baseline: 2.4308x; 2.4308x over previous
//
#include <hip/hip_runtime.h>

// Problem constants (match reference setup_inputs()).
#define Nn 50000
#define Rr 4
#define Dd 5
#define Ee 5000000
#define Bb 4
#define NRr (Nn * Rr)   // 200000
#define NDd (Nn * Dd)   // 250000
#define ZW 7814         // ceil(250000/32)=7813 (+1 guard word for ballot hi-write)

struct P {
    const float* inputs; const float* z_buf; const float* v; const float* r;
    const float* asc1; const float* asc2; const float* psc_rise; const float* psc;
    const float* rec_w; const int* rec_rows; const int* rec_cols;
    const float* syn_decay; const float* psc_initial; const float* t_ref;
    const float* asc_amps; const float* k; const float* v_th; const float* e_l;
    const float* v_reset; const float* g; const float* decay;
    const float* current_factor; const float* vscale; const float* voffset;
    float* out; float* i_rec; unsigned char* z_pack; unsigned* zbits;
};

// ---------------------------------------------------------------------------
// Kernel 1: zero i_rec, pack z_buf into per-column 4-bit batch masks (250 KB,
// L2-resident for edge gathers) + 1-bit OR-over-batches mask (31.3 KB -> LDS).
// ---------------------------------------------------------------------------
__global__ __launch_bounds__(256) void pack_z_kernel(P p) {
    int i = blockIdx.x * 256 + threadIdx.x;
    if (i < Bb * NRr / 4)
        ((float4*)p.i_rec)[i] = make_float4(0.f, 0.f, 0.f, 0.f);
    unsigned m = 0;
    if (i < NDd) {
#pragma unroll
        for (int b = 0; b < Bb; ++b)
            if (p.z_buf[(size_t)b * NDd + i] != 0.0f) m |= (1u << b);
        p.z_pack[i] = (unsigned char)m;
    }
    unsigned long long bal = __ballot(m != 0);
    if ((i & 63) == 0 && i < NDd) {
        p.zbits[(i >> 5)]     = (unsigned)bal;
        p.zbits[(i >> 5) + 1] = (unsigned)(bal >> 32);
    }
}

// ---------------------------------------------------------------------------
// Kernel 2: edge scatter (R1-proven structure: LDS bitmask gate -> z_pack
// byte -> fire-and-forget atomics) FUSED with all i_rec-INDEPENDENT neuron
// work. The edge path idles VALU+HBM (8.8%/12.8% in R1) waiting on the
// ~1-atomic/cy/XCD wall, so the streaming neuron work rides underneath.
// Output layout per batch (18*N floats):
//   [0,N)=new_z [N,2N)=out_v [2N,3N)=new_r [3N,4N)=asc1 [4N,5N)=asc2
//   [5N,9N)=psc_rise(kernel 3) [9N,13N)=psc [13N,18N)=shifted z_buf
// ---------------------------------------------------------------------------
__global__ __launch_bounds__(256) void edge_neuron_kernel(P p) {
    __shared__ unsigned zb[ZW];
    for (int t = threadIdx.x; t < ZW; t += 256) zb[t] = p.zbits[t];
    __syncthreads();
    const int tid = blockIdx.x * 256 + threadIdx.x;

    // ---- i_rec-independent neuron update (first 200k threads) ----
    if (tid < Bb * Nn) {
        int b = tid / Nn;
        int n = tid - b * Nn;
        const size_t bn  = (size_t)b * Nn + n;
        const size_t bnr = (size_t)b * NRr + (size_t)n * 4;

        float prev_z = p.z_buf[(size_t)b * NDd + n];
        float4 pr = *(const float4*)(p.psc_rise + bnr);
        float4 pc = *(const float4*)(p.psc + bnr);
        float4 sd = *(const float4*)(p.syn_decay + (size_t)n * 4);

        float4 npc;
        npc.x = pc.x * sd.x + sd.x * pr.x;
        npc.y = pc.y * sd.y + sd.y * pr.y;
        npc.z = pc.z * sd.z + sd.z * pr.z;
        npc.w = pc.w * sd.w + sd.w * pr.w;
        float input_current = pc.x + pc.y + pc.z + pc.w;   // OLD psc

        float new_r = fmaxf(p.r[bn] + prev_z * p.t_ref[n] - 1.0f, 0.0f);

        float2 kv = *(const float2*)(p.k + (size_t)n * 2);
        float2 aa = *(const float2*)(p.asc_amps + (size_t)n * 2);
        float kk0 = 1.0f / (1.0f + expf(-kv.x));
        float kk1 = 1.0f / (1.0f + expf(-kv.y));
        float a1 = p.asc1[bn];
        float a2 = p.asc2[bn];
        float na1 = expf(-kk0) * a1 + prev_z * aa.x;
        float na2 = expf(-kk1) * a2 + prev_z * aa.y;

        float vth = p.v_th[n];
        float el  = p.e_l[n];
        float reset_current = prev_z * (p.v_reset[n] - vth);
        float c1 = input_current + a1 + a2 + p.g[n] * el;  // OLD asc
        float new_v = p.decay[n] * p.v[bn] + p.current_factor[n] * c1
                      + reset_current;
        float v_sc = (new_v - vth) / (vth - el);
        float new_z = (v_sc > 0.0f) ? 1.0f : 0.0f;
        if (new_r > 0.0f) new_z = 0.0f;
        float out_v = new_v * p.vscale[n] + p.voffset[n];

        float* ob = p.out + (size_t)b * 18 * Nn;
        ob[n]          = new_z;
        ob[Nn + n]     = out_v;
        ob[2 * Nn + n] = new_r;
        ob[3 * Nn + n] = na1;
        ob[4 * Nn + n] = na2;
        *(float4*)(ob + 9 * Nn + (size_t)n * 4) = npc;
        ob[13 * Nn + n] = new_z;
#pragma unroll
        for (int d = 0; d < Dd - 1; ++d)
            ob[14 * Nn + (size_t)d * Nn + n] =
                p.z_buf[(size_t)b * NDd + (size_t)d * Nn + n];
    }

    // ---- edge scatter (one quad per thread, R1-proven) ----
    if (tid < Ee / 4) {
        int4 c = ((const int4*)p.rec_cols)[tid];
        unsigned h0 = (zb[(unsigned)c.x >> 5] >> (c.x & 31)) & 1u;
        unsigned h1 = (zb[(unsigned)c.y >> 5] >> (c.y & 31)) & 1u;
        unsigned h2 = (zb[(unsigned)c.z >> 5] >> (c.z & 31)) & 1u;
        unsigned h3 = (zb[(unsigned)c.w >> 5] >> (c.w & 31)) & 1u;
        if (h0 | h1 | h2 | h3) {
            int4 rw = ((const int4*)p.rec_rows)[tid];
            float4 w = ((const float4*)p.rec_w)[tid];
            float* i_rec = p.i_rec;
            auto do_edge = [&](unsigned hh, int col, int row, float wv) {
                if (hh) {
                    unsigned mm = p.z_pack[col];
                    if (mm & 1u) atomicAdd(&i_rec[0 * NRr + row], wv);
                    if (mm & 2u) atomicAdd(&i_rec[1 * NRr + row], wv);
                    if (mm & 4u) atomicAdd(&i_rec[2 * NRr + row], wv);
                    if (mm & 8u) atomicAdd(&i_rec[3 * NRr + row], wv);
                }
            };
            do_edge(h0, c.x, rw.x, w.x);
            do_edge(h1, c.y, rw.y, w.y);
            do_edge(h2, c.z, rw.z, w.z);
            do_edge(h3, c.w, rw.w, w.w);
        }
    }
}

// ---------------------------------------------------------------------------
// Kernel 3: the only i_rec consumer. npr = sd*pr + (i_rec+inputs)*pi.
// ~16 MB read + 3.2 MB write -> ~3 us.
// ---------------------------------------------------------------------------
__global__ __launch_bounds__(256) void psc_rise_kernel(P p) {
    int tid = blockIdx.x * 256 + threadIdx.x;
    if (tid >= Bb * Nn) return;
    int b = tid / Nn;
    int n = tid - b * Nn;
    const size_t bnr = (size_t)b * NRr + (size_t)n * 4;
    float4 ir  = *(const float4*)(p.i_rec + bnr);
    float4 in4 = *(const float4*)(p.inputs + bnr);
    float4 pr  = *(const float4*)(p.psc_rise + bnr);
    float4 sd  = *(const float4*)(p.syn_decay + (size_t)n * 4);
    float4 pi  = *(const float4*)(p.psc_initial + (size_t)n * 4);
    float4 npr;
    npr.x = sd.x * pr.x + (ir.x + in4.x) * pi.x;
    npr.y = sd.y * pr.y + (ir.y + in4.y) * pi.y;
    npr.z = sd.z * pr.z + (ir.z + in4.z) * pi.z;
    npr.w = sd.w * pr.w + (ir.w + in4.w) * pi.w;
    float* ob = p.out + (size_t)b * 18 * Nn;
    *(float4*)(ob + 5 * Nn + (size_t)n * 4) = npr;
}

extern "C" void kernel_launch(void* const* d_in, const int* in_sizes, int n_in,
                              void* d_out, int out_size, void* d_ws, size_t ws_size,
                              hipStream_t stream) {
    P p;
    p.inputs        = (const float*)d_in[0];
    p.z_buf         = (const float*)d_in[1];
    p.v             = (const float*)d_in[2];
    p.r             = (const float*)d_in[3];
    p.asc1          = (const float*)d_in[4];
    p.asc2          = (const float*)d_in[5];
    p.psc_rise      = (const float*)d_in[6];
    p.psc           = (const float*)d_in[7];
    p.rec_w         = (const float*)d_in[8];
    p.rec_rows      = (const int*)d_in[9];
    p.rec_cols      = (const int*)d_in[10];
    p.syn_decay     = (const float*)d_in[11];
    p.psc_initial   = (const float*)d_in[12];
    p.t_ref         = (const float*)d_in[13];
    p.asc_amps      = (const float*)d_in[14];
    p.k             = (const float*)d_in[15];
    p.v_th          = (const float*)d_in[16];
    p.e_l           = (const float*)d_in[17];
    p.v_reset       = (const float*)d_in[18];
    p.g             = (const float*)d_in[19];
    p.decay         = (const float*)d_in[20];
    p.current_factor= (const float*)d_in[21];
    p.vscale        = (const float*)d_in[22];
    p.voffset       = (const float*)d_in[23];
    p.out           = (float*)d_out;
    // Workspace: i_rec f32[800k] @0 | z_pack u8[250k] @3,200,000 |
    //            zbits u32[ZW] @3,450,240
    p.i_rec  = (float*)d_ws;
    p.z_pack = (unsigned char*)d_ws + 3200000;
    p.zbits  = (unsigned*)((char*)d_ws + 3450240);

    pack_z_kernel<<<(NDd + 255) / 256, 256, 0, stream>>>(p);
    edge_neuron_kernel<<<(Ee / 4 + 255) / 256, 256, 0, stream>>>(p);
    psc_rise_kernel<<<(Bb * Nn + 255) / 256, 256, 0, stream>>>(p);
}